// Round 7
// baseline (289.003 us; speedup 1.0000x reference)
//
#include <hip/hip_runtime.h>
#include <cstdint>

// Fisher-Kolmogorov explicit Euler, B=2, 128^3, up to 40 masked micro-steps.
// Round-7: T=2 fusion, square 8y x 8z tile (halo amp 2.25x vs 3.0x), s1 in
// LDS (51.2 KB, 3 blocks/CU). Phase 1a computes the s1 INTERIOR with the same
// thread->cell map as phase 2, keeping each cell's packed (D,rho) in registers
// (kills the phase-2 dr re-read, 17 MB/pair). Phase 1b fills the 36-row halo
// ring. u is read from global (L1 absorbs intra-block re-reads; rounds 5 vs 6
// showed LDS staging of u is neutral). z-rolling registers cut center loads.

constexpr int NX = 128, NY = 128, NZ = 128;
constexpr int PLANE = NX * NY;            // 16384
constexpr int VOL   = NZ * PLANE;         // 2,097,152
constexpr int TOTAL = 2 * VOL;            // 4,194,304
constexpr float DT  = 0.1f;               // MICRO_DT
constexpr int MAX_PAIRS = 20;             // 40 micro-steps / 2

constexpr int TY = 8, TZ = 8;             // block interior tile (x full 128)
constexpr int RY = TY + 2, RZ = TZ + 2;   // s1 region: 10 y x 10 z
constexpr int RING_ROWS = RZ * RY - TZ * TY;       // 36
constexpr int RING_F4   = RING_ROWS * 32;          // 1152
constexpr int BLOCKS = 2 * (NZ / TZ) * (NY / TY);  // 2*16*16 = 512

__device__ __forceinline__ float4 ld4(const float* p) { return *(const float4*)p; }

__device__ __forceinline__ uint32_t f2bf(float f) {
    uint32_t u = __float_as_uint(f);
    u += 0x7fffu + ((u >> 16) & 1u);      // round-to-nearest-even
    return u >> 16;
}
__device__ __forceinline__ float bf_lo(uint32_t p) { return __uint_as_float(p << 16); }
__device__ __forceinline__ float bf_hi(uint32_t p) { return __uint_as_float(p & 0xffff0000u); }
__device__ __forceinline__ float clip01(float v) { return fminf(fmaxf(v, 0.0f), 1.0f); }

__device__ __forceinline__ float4 fkstep(float4 c, float xm, float xp,
                                         float4 ym, float4 yp,
                                         float4 zm, float4 zp,
                                         float4 Dv, float4 Rv) {
    float4 o;
    o.x = fmaf(DT, fmaf(Dv.x, (xm + c.y) + (ym.x + yp.x) + (zm.x + zp.x) - 6.0f * c.x,
                        Rv.x * c.x * (1.0f - c.x)), c.x);
    o.y = fmaf(DT, fmaf(Dv.y, (c.x + c.z) + (ym.y + yp.y) + (zm.y + zp.y) - 6.0f * c.y,
                        Rv.y * c.y * (1.0f - c.y)), c.y);
    o.z = fmaf(DT, fmaf(Dv.z, (c.y + c.w) + (ym.z + yp.z) + (zm.z + zp.z) - 6.0f * c.z,
                        Rv.z * c.z * (1.0f - c.z)), c.z);
    o.w = fmaf(DT, fmaf(Dv.w, (c.z + xp) + (ym.w + yp.w) + (zm.w + zp.w) - 6.0f * c.w,
                        Rv.w * c.w * (1.0f - c.w)), c.w);
    return o;
}

__device__ __forceinline__ float4 unpackD(uint4 p) {
    return make_float4(bf_lo(p.x), bf_lo(p.y), bf_lo(p.z), bf_lo(p.w));
}
__device__ __forceinline__ float4 unpackR(uint4 p) {
    return make_float4(bf_hi(p.x), bf_hi(p.y), bf_hi(p.z), bf_hi(p.w));
}

__global__ __launch_bounds__(256, 2)
void fk_pair(const float* __restrict__ src, float* __restrict__ dst0,
             float* __restrict__ out, const float* __restrict__ u0,
             const float* __restrict__ Dm, const float* __restrict__ Rm,
             uint32_t* __restrict__ dr, const int* __restrict__ dtd, int p)
{
    const int b  = blockIdx.x >> 8;                  // batch item (block-uniform)
    int d = dtd[b]; d = d < 0 ? 0 : (d > 4 ? 4 : d);
    const int steps = d * 10;

    const int zb = (blockIdx.x >> 4) & 15;
    const int yt = blockIdx.x & 15;
    const int z0 = zb * TZ, y0 = yt * TY;
    const int tid = threadIdx.x;
    const int xq  = tid & 31;                        // float4 lane within row
    const int yi  = tid >> 5;                        // 0..7
    const int baseb = b << 21;
    const float4 zero = make_float4(0.f, 0.f, 0.f, 0.f);

    if (2 * p >= steps) {
        // d==0 items never get a step write: emit clip(u0) once, in pair 0.
        if (steps == 0 && p == 0) {
            #pragma unroll
            for (int k = 0; k < TZ; ++k) {
                const int idx = baseb + (z0 + k) * PLANE + (y0 + yi) * NX + (xq << 2);
                const float4 v = ld4(u0 + idx);
                float4 o;
                o.x = clip01(v.x); o.y = clip01(v.y);
                o.z = clip01(v.z); o.w = clip01(v.w);
                *(float4*)(out + idx) = o;
            }
        }
        return;                                      // block-uniform exit
    }
    const bool first = (p == 0);
    const bool last  = (2 * p == steps - 2);
    float* __restrict__ dst = last ? out : dst0;

    __shared__ float s1[RZ * RY * NX];               // 51.2 KiB step-1 region

    // ---- Phase 1a: step-1 on the INTERIOR (same thread->cell map as phase
    // 2), packed dr kept in registers; z-rolling center planes. ----
    uint4 pr[TZ];                                    // 32 VGPRs of (D,rho) bf16
    {
        const int y = y0 + yi;                       // always in-domain
        const int colbase = baseb + y * NX + (xq << 2);
        const bool has_ym = (y > 0), has_yp = (y < NY - 1);
        const bool has_l = (xq > 0), has_r = (xq < 31);

        float4 um = (z0 > 0) ? ld4(src + colbase + (z0 - 1) * PLANE) : zero;
        float4 uc = ld4(src + colbase + z0 * PLANE);
        #pragma unroll
        for (int k = 0; k < TZ; ++k) {
            const int z = z0 + k;
            const int idx = colbase + z * PLANE;
            const float4 un = (z < NZ - 1) ? ld4(src + idx + PLANE) : zero;
            const float4 ym4 = has_ym ? ld4(src + idx - NX) : zero;
            const float4 yp4 = has_yp ? ld4(src + idx + NX) : zero;
            const float xm = has_l ? src[idx - 1] : 0.0f;
            const float xp = has_r ? src[idx + 4] : 0.0f;
            float4 Dv, Rv;
            if (first) {
                Dv = ld4(Dm + idx);
                Rv = ld4(Rm + idx);
                uint4 pk;
                pk.x = f2bf(Dv.x) | (f2bf(Rv.x) << 16);
                pk.y = f2bf(Dv.y) | (f2bf(Rv.y) << 16);
                pk.z = f2bf(Dv.z) | (f2bf(Rv.z) << 16);
                pk.w = f2bf(Dv.w) | (f2bf(Rv.w) << 16);
                *(uint4*)(dr + idx) = pk;            // publish for pairs >= 1
                pr[k] = pk;
            } else {
                pr[k] = *(const uint4*)(dr + idx);
                Dv = unpackD(pr[k]);
                Rv = unpackR(pr[k]);
            }
            const float4 o = fkstep(uc, xm, xp, ym4, yp4, um, un, Dv, Rv);
            *(float4*)&s1[((k + 1) * RY + (yi + 1)) * NX + (xq << 2)] = o;
            um = uc; uc = un;
        }
    }

    // ---- Phase 1b: step-1 on the 36-row halo ring ----
    for (int i = tid; i < RING_F4; i += 256) {
        const int cxq = i & 31;
        const int r   = i >> 5;                      // ring row 0..35
        int rz, ry;
        if (r < 10)      { rz = 0; ry = r; }
        else if (r < 20) { rz = 9; ry = r - 10; }
        else { const int q = r - 20; rz = 1 + (q >> 1); ry = (q & 1) ? 9 : 0; }
        const int y = y0 - 1 + ry;
        const int z = z0 - 1 + rz;
        float4 o = zero;                             // out-of-domain -> 0
        if ((unsigned)y < (unsigned)NY && (unsigned)z < (unsigned)NZ) {
            const int idx = baseb + z * PLANE + y * NX + (cxq << 2);
            const float4 c  = ld4(src + idx);
            const float xm  = (cxq > 0)  ? src[idx - 1] : 0.0f;
            const float xp  = (cxq < 31) ? src[idx + 4] : 0.0f;
            const float4 ym4 = (y > 0)      ? ld4(src + idx - NX)    : zero;
            const float4 yp4 = (y < NY - 1) ? ld4(src + idx + NX)    : zero;
            const float4 zm4 = (z > 0)      ? ld4(src + idx - PLANE) : zero;
            const float4 zp4 = (z < NZ - 1) ? ld4(src + idx + PLANE) : zero;
            float4 Dv, Rv;
            if (first) {                             // neighbor dr not yet visible
                Dv = ld4(Dm + idx);
                Rv = ld4(Rm + idx);
            } else {
                const uint4 pk = *(const uint4*)(dr + idx);
                Dv = unpackD(pk);
                Rv = unpackR(pk);
            }
            o = fkstep(c, xm, xp, ym4, yp4, zm4, zp4, Dv, Rv);
        }
        *(float4*)&s1[(rz * RY + ry) * NX + (cxq << 2)] = o;
    }
    __syncthreads();

    // ---- Phase 2: step-2 on the interior from LDS s1, dr from registers ----
    {
        const int ry = yi + 1;
        const int y  = y0 + yi;
        float4 zmv = *(const float4*)&s1[(0 * RY + ry) * NX + (xq << 2)];
        float4 cv  = *(const float4*)&s1[(1 * RY + ry) * NX + (xq << 2)];
        #pragma unroll
        for (int k = 0; k < TZ; ++k) {
            const int rz = k + 1;
            const float4 zpv = *(const float4*)&s1[((rz + 1) * RY + ry) * NX + (xq << 2)];
            const float* rowc = &s1[(rz * RY + ry) * NX];
            float xm = 0.0f, xp = 0.0f;
            if (xq > 0)  xm = ((const float4*)&rowc[(xq - 1) << 2])->w;
            if (xq < 31) xp = ((const float4*)&rowc[(xq + 1) << 2])->x;
            const float4 ym4 = *(const float4*)&s1[(rz * RY + ry - 1) * NX + (xq << 2)];
            const float4 yp4 = *(const float4*)&s1[(rz * RY + ry + 1) * NX + (xq << 2)];

            float4 o = fkstep(cv, xm, xp, ym4, yp4, zmv, zpv,
                              unpackD(pr[k]), unpackR(pr[k]));
            if (last) {
                o.x = clip01(o.x); o.y = clip01(o.y);
                o.z = clip01(o.z); o.w = clip01(o.w);
            }
            const int idx = baseb + (z0 + k) * PLANE + y * NX + (xq << 2);
            *(float4*)(dst + idx) = o;
            zmv = cv; cv = zpv;
        }
    }
}

extern "C" void kernel_launch(void* const* d_in, const int* in_sizes, int n_in,
                              void* d_out, int out_size, void* d_ws, size_t ws_size,
                              hipStream_t stream) {
    const float* u0  = (const float*)d_in[0];
    const float* Dm  = (const float*)d_in[1];
    const float* Rm  = (const float*)d_in[2];
    const int*   dtd = (const int*)d_in[3];
    float* out = (float*)d_out;
    float* ws  = (float*)d_ws;
    // ws layout: [0,16M) buf0, [16M,32M) buf1, [32M,48M) packed DR (ws=256MB).
    float* buf[2] = { ws, ws + TOTAL };
    uint32_t* dr = (uint32_t*)(ws + 2 * TOTAL);

    // Pair p advances steps 2p,2p+1. src: u0 for p=0 else buf[(p-1)&1];
    // normal dst alternates buf[p&1]; an item's LAST pair redirects to `out`
    // (clipped) on-device. d==0 items emit clip(u0) during pair 0.
    for (int p = 0; p < MAX_PAIRS; ++p) {
        const float* src = (p == 0) ? u0 : buf[(p - 1) & 1];
        fk_pair<<<BLOCKS, 256, 0, stream>>>(src, buf[p & 1], out, u0,
                                            Dm, Rm, dr, dtd, p);
    }
}

// Round 9
// 243.470 us; speedup vs baseline: 1.1870x; 1.1870x over previous
//
#include <hip/hip_runtime.h>
#include <cstdint>

// Fisher-Kolmogorov explicit Euler, B=2, 128^3, up to 40 masked micro-steps.
// Round-9 = R5's occupancy shape (8y x 4z tile, 1024 blocks, 30 KB LDS,
// 4 blocks/CU = 16 waves/CU) + proven occupancy-neutral byte cuts from R7:
//  - phase 1a computes s1 interior with the phase-2 thread map, carrying
//    packed (D,rho) bf16 in registers (no phase-2 dr re-read)
//  - z-rolled center planes (1 center load/cell instead of 3)
//  - x-neighbors via scalar global loads (1a) / LDS f4-extracts (2) — the
//    R8 shfl exchange failed correctness and is reverted.
// Evidence: R5=248us @16 waves/CU; R6/R7 byte cuts at 8 waves/CU regressed
// -> occupancy dominates; bytes only pay at constant occupancy.

constexpr int NX = 128, NY = 128, NZ = 128;
constexpr int PLANE = NX * NY;            // 16384
constexpr int VOL   = NZ * PLANE;         // 2,097,152
constexpr int TOTAL = 2 * VOL;            // 4,194,304
constexpr float DT  = 0.1f;               // MICRO_DT
constexpr int MAX_PAIRS = 20;             // 40 micro-steps / 2

constexpr int TY = 8, TZ = 4;             // block interior tile (x full 128)
constexpr int RY = TY + 2, RZ = TZ + 2;   // s1 region: 10 y x 6 z
constexpr int RING_ROWS = RZ * RY - TZ * TY;       // 28
constexpr int RING_F4   = RING_ROWS * 32;          // 896
constexpr int BLOCKS = 2 * (NZ / TZ) * (NY / TY);  // 2*32*16 = 1024

__device__ __forceinline__ float4 ld4(const float* p) { return *(const float4*)p; }

__device__ __forceinline__ uint32_t f2bf(float f) {
    uint32_t u = __float_as_uint(f);
    u += 0x7fffu + ((u >> 16) & 1u);      // round-to-nearest-even
    return u >> 16;
}
__device__ __forceinline__ float bf_lo(uint32_t p) { return __uint_as_float(p << 16); }
__device__ __forceinline__ float bf_hi(uint32_t p) { return __uint_as_float(p & 0xffff0000u); }
__device__ __forceinline__ float clip01(float v) { return fminf(fmaxf(v, 0.0f), 1.0f); }

__device__ __forceinline__ float4 fkstep(float4 c, float xm, float xp,
                                         float4 ym, float4 yp,
                                         float4 zm, float4 zp,
                                         float4 Dv, float4 Rv) {
    float4 o;
    o.x = fmaf(DT, fmaf(Dv.x, (xm + c.y) + (ym.x + yp.x) + (zm.x + zp.x) - 6.0f * c.x,
                        Rv.x * c.x * (1.0f - c.x)), c.x);
    o.y = fmaf(DT, fmaf(Dv.y, (c.x + c.z) + (ym.y + yp.y) + (zm.y + zp.y) - 6.0f * c.y,
                        Rv.y * c.y * (1.0f - c.y)), c.y);
    o.z = fmaf(DT, fmaf(Dv.z, (c.y + c.w) + (ym.z + yp.z) + (zm.z + zp.z) - 6.0f * c.z,
                        Rv.z * c.z * (1.0f - c.z)), c.z);
    o.w = fmaf(DT, fmaf(Dv.w, (c.z + xp) + (ym.w + yp.w) + (zm.w + zp.w) - 6.0f * c.w,
                        Rv.w * c.w * (1.0f - c.w)), c.w);
    return o;
}

__device__ __forceinline__ float4 unpackD(uint4 p) {
    return make_float4(bf_lo(p.x), bf_lo(p.y), bf_lo(p.z), bf_lo(p.w));
}
__device__ __forceinline__ float4 unpackR(uint4 p) {
    return make_float4(bf_hi(p.x), bf_hi(p.y), bf_hi(p.z), bf_hi(p.w));
}

__global__ __launch_bounds__(256, 4)
void fk_pair(const float* __restrict__ src, float* __restrict__ dst0,
             float* __restrict__ out, const float* __restrict__ u0,
             const float* __restrict__ Dm, const float* __restrict__ Rm,
             uint32_t* __restrict__ dr, const int* __restrict__ dtd, int p)
{
    const int b  = blockIdx.x >> 9;                  // batch item (block-uniform)
    int d = dtd[b]; d = d < 0 ? 0 : (d > 4 ? 4 : d);
    const int steps = d * 10;

    const int zb = (blockIdx.x >> 4) & 31;
    const int yt = blockIdx.x & 15;
    const int z0 = zb * TZ, y0 = yt * TY;
    const int tid = threadIdx.x;
    const int xq  = tid & 31;                        // float4 lane within row
    const int yi  = tid >> 5;                        // 0..7
    const int baseb = b << 21;
    const float4 zero = make_float4(0.f, 0.f, 0.f, 0.f);

    if (2 * p >= steps) {
        // d==0 items never get a step write: emit clip(u0) once, in pair 0.
        if (steps == 0 && p == 0) {
            #pragma unroll
            for (int k = 0; k < TZ; ++k) {
                const int idx = baseb + (z0 + k) * PLANE + (y0 + yi) * NX + (xq << 2);
                const float4 v = ld4(u0 + idx);
                float4 o;
                o.x = clip01(v.x); o.y = clip01(v.y);
                o.z = clip01(v.z); o.w = clip01(v.w);
                *(float4*)(out + idx) = o;
            }
        }
        return;                                      // block-uniform exit
    }
    const bool first = (p == 0);
    const bool last  = (2 * p == steps - 2);
    float* __restrict__ dst = last ? out : dst0;

    __shared__ float s1[RZ * RY * NX];               // 30 KiB step-1 region

    // ---- Phase 1a: step-1 on the INTERIOR (same thread->cell map as phase
    // 2); packed dr carried in registers; z-rolled center planes. ----
    uint4 pr[TZ];                                    // 16 VGPRs of (D,rho) bf16
    {
        const int y = y0 + yi;                       // in-domain by construction
        const int colbase = baseb + y * NX + (xq << 2);
        const bool has_ym = (y > 0), has_yp = (y < NY - 1);
        const bool has_l = (xq > 0), has_r = (xq < 31);

        float4 um = (z0 > 0) ? ld4(src + colbase + (z0 - 1) * PLANE) : zero;
        float4 uc = ld4(src + colbase + z0 * PLANE);
        #pragma unroll
        for (int k = 0; k < TZ; ++k) {
            const int z = z0 + k;
            const int idx = colbase + z * PLANE;
            const float4 un = (z < NZ - 1) ? ld4(src + idx + PLANE) : zero;
            const float4 ym4 = has_ym ? ld4(src + idx - NX) : zero;
            const float4 yp4 = has_yp ? ld4(src + idx + NX) : zero;
            const float xm = has_l ? src[idx - 1] : 0.0f;
            const float xp = has_r ? src[idx + 4] : 0.0f;
            float4 Dv, Rv;
            if (first) {
                Dv = ld4(Dm + idx);
                Rv = ld4(Rm + idx);
                uint4 pk;
                pk.x = f2bf(Dv.x) | (f2bf(Rv.x) << 16);
                pk.y = f2bf(Dv.y) | (f2bf(Rv.y) << 16);
                pk.z = f2bf(Dv.z) | (f2bf(Rv.z) << 16);
                pk.w = f2bf(Dv.w) | (f2bf(Rv.w) << 16);
                *(uint4*)(dr + idx) = pk;            // publish for pairs >= 1
                pr[k] = pk;
            } else {
                pr[k] = *(const uint4*)(dr + idx);
                Dv = unpackD(pr[k]);
                Rv = unpackR(pr[k]);
            }
            const float4 o = fkstep(uc, xm, xp, ym4, yp4, um, un, Dv, Rv);
            *(float4*)&s1[((k + 1) * RY + (yi + 1)) * NX + (xq << 2)] = o;
            um = uc; uc = un;
        }
    }

    // ---- Phase 1b: step-1 on the 28-row halo ring (global loads) ----
    for (int i = tid; i < RING_F4; i += 256) {
        const int cxq = i & 31;
        const int r   = i >> 5;                      // ring row 0..27
        int rz, ry;
        if (r < 10)      { rz = 0; ry = r; }
        else if (r < 20) { rz = 5; ry = r - 10; }
        else { const int q = r - 20; rz = 1 + (q >> 1); ry = (q & 1) ? 9 : 0; }
        const int y = y0 - 1 + ry;
        const int z = z0 - 1 + rz;
        float4 o = zero;                             // out-of-domain -> 0
        if ((unsigned)y < (unsigned)NY && (unsigned)z < (unsigned)NZ) {
            const int idx = baseb + z * PLANE + y * NX + (cxq << 2);
            const float4 c  = ld4(src + idx);
            const float xm  = (cxq > 0)  ? src[idx - 1] : 0.0f;
            const float xp  = (cxq < 31) ? src[idx + 4] : 0.0f;
            const float4 ym4 = (y > 0)      ? ld4(src + idx - NX)    : zero;
            const float4 yp4 = (y < NY - 1) ? ld4(src + idx + NX)    : zero;
            const float4 zm4 = (z > 0)      ? ld4(src + idx - PLANE) : zero;
            const float4 zp4 = (z < NZ - 1) ? ld4(src + idx + PLANE) : zero;
            float4 Dv, Rv;
            if (first) {
                Dv = ld4(Dm + idx);
                Rv = ld4(Rm + idx);
            } else {
                const uint4 pk = *(const uint4*)(dr + idx);
                Dv = unpackD(pk);
                Rv = unpackR(pk);
            }
            o = fkstep(c, xm, xp, ym4, yp4, zm4, zp4, Dv, Rv);
        }
        *(float4*)&s1[(rz * RY + ry) * NX + (cxq << 2)] = o;
    }
    __syncthreads();

    // ---- Phase 2: step-2 on the interior from LDS s1; dr from registers;
    // x-neighbors via LDS f4-extracts; z-rolled s1 planes. ----
    {
        const int ry = yi + 1;
        const int y  = y0 + yi;
        float4 zmv = *(const float4*)&s1[(0 * RY + ry) * NX + (xq << 2)];
        float4 cv  = *(const float4*)&s1[(1 * RY + ry) * NX + (xq << 2)];
        #pragma unroll
        for (int k = 0; k < TZ; ++k) {
            const int rz = k + 1;
            const float4 zpv = *(const float4*)&s1[((rz + 1) * RY + ry) * NX + (xq << 2)];
            const float* rowc = &s1[(rz * RY + ry) * NX];
            float xm = 0.0f, xp = 0.0f;
            if (xq > 0)  xm = ((const float4*)&rowc[(xq - 1) << 2])->w;
            if (xq < 31) xp = ((const float4*)&rowc[(xq + 1) << 2])->x;
            const float4 ym4 = *(const float4*)&s1[(rz * RY + ry - 1) * NX + (xq << 2)];
            const float4 yp4 = *(const float4*)&s1[(rz * RY + ry + 1) * NX + (xq << 2)];

            float4 o = fkstep(cv, xm, xp, ym4, yp4, zmv, zpv,
                              unpackD(pr[k]), unpackR(pr[k]));
            if (last) {
                o.x = clip01(o.x); o.y = clip01(o.y);
                o.z = clip01(o.z); o.w = clip01(o.w);
            }
            const int idx = baseb + (z0 + k) * PLANE + y * NX + (xq << 2);
            *(float4*)(dst + idx) = o;
            zmv = cv; cv = zpv;
        }
    }
}

extern "C" void kernel_launch(void* const* d_in, const int* in_sizes, int n_in,
                              void* d_out, int out_size, void* d_ws, size_t ws_size,
                              hipStream_t stream) {
    const float* u0  = (const float*)d_in[0];
    const float* Dm  = (const float*)d_in[1];
    const float* Rm  = (const float*)d_in[2];
    const int*   dtd = (const int*)d_in[3];
    float* out = (float*)d_out;
    float* ws  = (float*)d_ws;
    // ws layout: [0,16M) buf0, [16M,32M) buf1, [32M,48M) packed DR (ws=256MB).
    float* buf[2] = { ws, ws + TOTAL };
    uint32_t* dr = (uint32_t*)(ws + 2 * TOTAL);

    // Pair p advances steps 2p,2p+1. src: u0 for p=0 else buf[(p-1)&1];
    // normal dst alternates buf[p&1]; an item's LAST pair redirects to `out`
    // (clipped) on-device. d==0 items emit clip(u0) during pair 0.
    for (int p = 0; p < MAX_PAIRS; ++p) {
        const float* src = (p == 0) ? u0 : buf[(p - 1) & 1];
        fk_pair<<<BLOCKS, 256, 0, stream>>>(src, buf[p & 1], out, u0,
                                            Dm, Rm, dr, dtd, p);
    }
}